// Round 7
// baseline (137.817 us; speedup 1.0000x reference)
//
#include <hip/hip_runtime.h>
#include <math.h>

#define NT 32768
#define DIM 256
#define NE 16
#define EH 128
#define RH 64
#define TB 64

// ws layout: float part1[NT*DIM] first, then int/float bookkeeping, then bf16 weights
#define IB (NT * DIM)
#define WS_COUNTS (IB)
#define WS_OFFSETS (IB + 16)
#define WS_CURSORS (IB + 33)
#define WS_NBLK (IB + 49)
#define WS_TABLE (IB + 64)
#define WS_TOKE (IB + 4096)
#define WS_LIST (WS_TOKE + 2 * NT)
#define WS_TOKG (WS_LIST + 2 * NT)
#define WS_LIST_G (WS_TOKG + 2 * NT)
#define WS_END_I (WS_LIST_G + 2 * NT)
// ushort-unit offsets for bf16 transposed weights
#define U_W1T (2 * WS_END_I)
#define U_W2T (U_W1T + NE * DIM * EH)

typedef __attribute__((ext_vector_type(4))) float f32x4;
typedef __attribute__((ext_vector_type(8))) short bf16x8;
typedef __attribute__((ext_vector_type(8))) unsigned short us8;

// XOR swizzles: SWZ9 for 512B-stride tiles (row bits 9-11 -> byte bits 4-6),
//               SWZ8 for 256B-stride tiles (row bits 8-10 -> byte bits 4-6)
#define SWZ9(b) ((b) ^ (((b) >> 5) & 0x70))
#define SWZ8(b) ((b) ^ (((b) >> 4) & 0x70))

__device__ inline unsigned short f2bf(float f) {
    unsigned int bits = __builtin_bit_cast(unsigned int, f);
    bits += 0x7fffu + ((bits >> 16) & 1u);   // RNE
    return (unsigned short)(bits >> 16);
}

// ---------------- Router: w = softmax(relu(x@rw1+b1)@rw2+b2), top-2 ----------------
__global__ __launch_bounds__(256) void router_kernel(
    const float* __restrict__ x,
    const float* __restrict__ rw1, const float* __restrict__ rb1,
    const float* __restrict__ rw2, const float* __restrict__ rb2,
    float* __restrict__ w_out, int* __restrict__ wsi, float* __restrict__ wsf)
{
    __shared__ float xT[64][68];   // [d-chunk][tok]
    __shared__ float w1s[64][64];  // [d][h]
    __shared__ float hs[64][68];   // [tok][h]
    __shared__ float ls[64][20];   // [tok][e]
    __shared__ int scnt[16];

    const int tid = threadIdx.x;
    const int tok0 = blockIdx.x * 64;
    if (tid < 16) scnt[tid] = 0;

    float acc[4][4];
#pragma unroll
    for (int i = 0; i < 4; ++i)
#pragma unroll
        for (int j = 0; j < 4; ++j) acc[i][j] = 0.f;

    const int tt = (tid & 15) * 4;
    const int hh = (tid >> 4) * 4;

    for (int kc = 0; kc < 4; ++kc) {
        __syncthreads();
#pragma unroll
        for (int i = 0; i < 4; ++i) {
            int idx = tid + 256 * i;
            int t = idx >> 4;
            int d4 = (idx & 15) * 4;
            float4 v = *(const float4*)(x + (size_t)(tok0 + t) * DIM + kc * 64 + d4);
            xT[d4 + 0][t] = v.x; xT[d4 + 1][t] = v.y;
            xT[d4 + 2][t] = v.z; xT[d4 + 3][t] = v.w;
        }
#pragma unroll
        for (int i = 0; i < 4; ++i) {
            int idx = tid + 256 * i;
            int d = idx >> 4;
            int h4 = (idx & 15) * 4;
            *(float4*)&w1s[d][h4] = *(const float4*)(rw1 + (size_t)(kc * 64 + d) * RH + h4);
        }
        __syncthreads();
#pragma unroll 8
        for (int d = 0; d < 64; ++d) {
            const float4 xa4 = *(const float4*)&xT[d][tt];
            const float4 wv4 = *(const float4*)&w1s[d][hh];
            const float xa[4] = {xa4.x, xa4.y, xa4.z, xa4.w};
            const float wv[4] = {wv4.x, wv4.y, wv4.z, wv4.w};
#pragma unroll
            for (int i = 0; i < 4; ++i)
#pragma unroll
                for (int j = 0; j < 4; ++j)
                    acc[i][j] = fmaf(xa[i], wv[j], acc[i][j]);
        }
    }
    __syncthreads();
    {
        const float4 b4 = *(const float4*)(rb1 + hh);
        const float b[4] = {b4.x, b4.y, b4.z, b4.w};
#pragma unroll
        for (int i = 0; i < 4; ++i) {
            float4 hv;
            hv.x = fmaxf(acc[i][0] + b[0], 0.f);
            hv.y = fmaxf(acc[i][1] + b[1], 0.f);
            hv.z = fmaxf(acc[i][2] + b[2], 0.f);
            hv.w = fmaxf(acc[i][3] + b[3], 0.f);
            *(float4*)&hs[tt + i][hh] = hv;
        }
    }
    __syncthreads();
    {
        int tok = tid >> 2;
        int e0 = (tid & 3) * 4;
        float l[4] = {0.f, 0.f, 0.f, 0.f};
#pragma unroll 8
        for (int k = 0; k < 64; ++k) {
            float hv = hs[tok][k];
            float4 wv = *(const float4*)(rw2 + k * NE + e0);
            l[0] = fmaf(hv, wv.x, l[0]);
            l[1] = fmaf(hv, wv.y, l[1]);
            l[2] = fmaf(hv, wv.z, l[2]);
            l[3] = fmaf(hv, wv.w, l[3]);
        }
        float4 lb = *(const float4*)(rb2 + e0);
        ls[tok][e0 + 0] = l[0] + lb.x;
        ls[tok][e0 + 1] = l[1] + lb.y;
        ls[tok][e0 + 2] = l[2] + lb.z;
        ls[tok][e0 + 3] = l[3] + lb.w;
    }
    __syncthreads();
    if (tid < 64) {
        const int tok = tid;
        const int gt = tok0 + tok;
        float v[16];
        float m = -1e30f;
#pragma unroll
        for (int e = 0; e < 16; ++e) { v[e] = ls[tok][e]; m = fmaxf(m, v[e]); }
        float s = 0.f;
#pragma unroll
        for (int e = 0; e < 16; ++e) { v[e] = expf(v[e] - m); s += v[e]; }
        const float inv = 1.0f / s;
#pragma unroll
        for (int e = 0; e < 16; ++e) v[e] *= inv;
#pragma unroll
        for (int e = 0; e < 16; e += 4) {
            float4 wv = make_float4(v[e], v[e + 1], v[e + 2], v[e + 3]);
            *(float4*)(w_out + (size_t)gt * NE + e) = wv;
        }
        float v1 = -1.f, v2 = -1.f; int i1 = 0, i2 = 0;
#pragma unroll
        for (int e = 0; e < 16; ++e) {
            if (v[e] > v1) { v2 = v1; i2 = i1; v1 = v[e]; i1 = e; }
            else if (v[e] > v2) { v2 = v[e]; i2 = e; }
        }
        const float den = v1 + v2 + 1e-8f;
        atomicAdd(&scnt[i1], 1);
        atomicAdd(&scnt[i2], 1);
        wsi[WS_TOKE + 2 * gt + 0] = i1;
        wsi[WS_TOKE + 2 * gt + 1] = i2;
        wsf[WS_TOKG + 2 * gt + 0] = v1 / den;
        wsf[WS_TOKG + 2 * gt + 1] = v2 / den;
    }
    __syncthreads();
    if (tid < 16 && scnt[tid]) atomicAdd(&wsi[WS_COUNTS + tid], scnt[tid]);
}

// ---------------- Weight prep: transpose + convert to bf16 ----------------
// w1t[e][h=128][d=256] = bf16(ew1[e][d][h]);  w2t[e][d=256][k=128] = bf16(ew2[e][k][d])
__global__ __launch_bounds__(256) void wprep_kernel(
    const float* __restrict__ ew1, const float* __restrict__ ew2,
    unsigned short* __restrict__ w1t, unsigned short* __restrict__ w2t)
{
    __shared__ float t[64][65];
    int b = blockIdx.x;
    const float* src; unsigned short* dst; int R, C, tr, tc;
    if (b < 128) {                 // w1: [256 d][128 h] -> [128 h][256 d], 4x2 tiles
        int e = b >> 3, t8 = b & 7; tr = t8 >> 1; tc = t8 & 1;
        src = ew1 + (size_t)e * DIM * EH; R = DIM; C = EH;
        dst = w1t + (size_t)e * DIM * EH;
    } else {                       // w2: [128 k][256 d] -> [256 d][128 k], 2x4 tiles
        int b2 = b - 128; int e = b2 >> 3, t8 = b2 & 7; tr = t8 & 1; tc = t8 >> 1;
        src = ew2 + (size_t)e * EH * DIM; R = EH; C = DIM;
        dst = w2t + (size_t)e * EH * DIM;
    }
    const int R0 = tr * 64, C0 = tc * 64;
    const int tid = threadIdx.x;
#pragma unroll
    for (int q = 0; q < 4; ++q) {
        int r = (tid >> 4) + q * 16, c = (tid & 15) * 4;
        float4 v = *(const float4*)(src + (size_t)(R0 + r) * C + C0 + c);
        t[r][c] = v.x; t[r][c + 1] = v.y; t[r][c + 2] = v.z; t[r][c + 3] = v.w;
    }
    __syncthreads();
#pragma unroll
    for (int q = 0; q < 2; ++q) {
        int rp = (tid >> 3) + q * 32, c0 = (tid & 7) * 8;
        us8 u;
#pragma unroll
        for (int k = 0; k < 8; ++k) u[k] = f2bf(t[c0 + k][rp]);
        *(us8*)(dst + (size_t)(C0 + rp) * R + R0 + c0) = u;
    }
}

// ---------------- Scan ----------------
__global__ __launch_bounds__(64) void scan_kernel(int* __restrict__ wsi)
{
    __shared__ int soff[17], snc[16];
    const int tid = threadIdx.x;
    if (tid == 0) {
        int off = 0, nb = 0;
        soff[0] = 0;
        for (int e = 0; e < NE; ++e) {
            int c = wsi[WS_COUNTS + e];
            wsi[WS_CURSORS + e] = off;
            wsi[WS_OFFSETS + e] = off;
            off += c;
            soff[e + 1] = off;
            snc[e] = nb;
            nb += (c + TB - 1) / TB;
        }
        wsi[WS_OFFSETS + NE] = off;
        wsi[WS_NBLK] = nb;
    }
    __syncthreads();
    for (int e = 0; e < NE; ++e) {
        int nc = (soff[e + 1] - soff[e] + TB - 1) / TB;
        for (int k = tid; k < nc; k += 64)
            wsi[WS_TABLE + snc[e] + k] = (e << 16) | k;
    }
}

// ---------------- Scatter ----------------
__global__ __launch_bounds__(256) void scatter_kernel(int* __restrict__ wsi, float* __restrict__ wsf)
{
    __shared__ int scnt[16], sbase[16];
    const int tid = threadIdx.x;
    const int t = blockIdx.x * 256 + tid;
    if (tid < 16) scnt[tid] = 0;
    __syncthreads();
    const int e0 = wsi[WS_TOKE + 2 * t + 0];
    const int e1 = wsi[WS_TOKE + 2 * t + 1];
    const int l0 = atomicAdd(&scnt[e0], 1);
    const int l1 = atomicAdd(&scnt[e1], 1);
    __syncthreads();
    if (tid < 16) sbase[tid] = scnt[tid] ? atomicAdd(&wsi[WS_CURSORS + tid], scnt[tid]) : 0;
    __syncthreads();
    const int p0 = sbase[e0] + l0;
    const int p1 = sbase[e1] + l1;
    wsi[WS_LIST + p0] = (t << 1);
    wsf[WS_LIST_G + p0] = wsf[WS_TOKG + 2 * t + 0];
    wsi[WS_LIST + p1] = (t << 1) | 1;
    wsf[WS_LIST_G + p1] = wsf[WS_TOKG + 2 * t + 1];
}

// ---------------- Expert: TB=64, 4 waves, full register-prefetch of weight panels ----------------
__global__ __launch_bounds__(256, 4) void expert_kernel(
    const float* __restrict__ x,
    const float* __restrict__ eb1, const float* __restrict__ eb2,
    const unsigned short* __restrict__ w1t, const unsigned short* __restrict__ w2t,
    const int* __restrict__ wsi, const float* __restrict__ wsf,
    float* __restrict__ y, float* __restrict__ part1)
{
    __shared__ unsigned short smem[16384];   // 32 KB: Xs[64][256] bf16, later hT[64][128] bf16
    if ((int)blockIdx.x >= wsi[WS_NBLK]) return;

    const int ent = wsi[WS_TABLE + blockIdx.x];
    const int e = ent >> 16;
    const int c = ent & 0xffff;
    const int start = wsi[WS_OFFSETS + e] + c * TB;
    const int cnt = min(TB, wsi[WS_OFFSETS + e + 1] - start);

    const int tid = threadIdx.x;
    const int lane = tid & 63, w = tid >> 6;   // wave 0..3
    const int l15 = lane & 15;
    const int kq = lane >> 4;                   // 0..3
    const int q4 = kq * 4;
    char* lds = (char*)smem;

    // ---- prefetch ALL phase-1 W1 fragments into registers (one L2 round-trip for 8 K-steps) ----
    const char* w1e = (const char*)(w1t + (size_t)e * DIM * EH);
    bf16x8 b1[8][2];
#pragma unroll
    for (int ks = 0; ks < 8; ++ks)
#pragma unroll
        for (int nt = 0; nt < 2; ++nt)
            b1[ks][nt] = *(const bf16x8*)(w1e + (w * 32 + nt * 16 + l15) * 512 + ks * 64 + kq * 16);

    // ---- stage Xs[64 tok][256 d] bf16 (fp32->bf16 gather), SWZ9 swizzled ----
    {
        const int row = tid >> 2, q = tid & 3;
        const int srow = (row < cnt) ? (wsi[WS_LIST + start + row] >> 1) : -1;
        const float* xr = x + (size_t)(srow < 0 ? 0 : srow) * DIM + q * 64;
        const int base = row * 512 + q * 128;
#pragma unroll
        for (int i = 0; i < 8; ++i) {
            us8 u;
            if (srow >= 0) {
                float4 a = *(const float4*)(xr + i * 8);
                float4 b = *(const float4*)(xr + i * 8 + 4);
                u[0] = f2bf(a.x); u[1] = f2bf(a.y); u[2] = f2bf(a.z); u[3] = f2bf(a.w);
                u[4] = f2bf(b.x); u[5] = f2bf(b.y); u[6] = f2bf(b.z); u[7] = f2bf(b.w);
            } else {
#pragma unroll
                for (int k = 0; k < 8; ++k) u[k] = 0;
            }
            *(us8*)(lds + SWZ9(base + i * 16)) = u;
        }
    }
    __syncthreads();

    // ---- phase 1: C1[64 tok][32 h per wave] = X @ W1, K=256, B pre-loaded ----
    f32x4 zero4; zero4[0] = zero4[1] = zero4[2] = zero4[3] = 0.f;
    f32x4 acc[4][2];
#pragma unroll
    for (int i = 0; i < 4; ++i)
#pragma unroll
        for (int j = 0; j < 2; ++j) acc[i][j] = zero4;

#pragma unroll
    for (int ks = 0; ks < 8; ++ks) {
        bf16x8 a[4];
#pragma unroll
        for (int mt = 0; mt < 4; ++mt)
            a[mt] = *(const bf16x8*)(lds + SWZ9((mt * 16 + l15) * 512 + ks * 64 + kq * 16));
#pragma unroll
        for (int mt = 0; mt < 4; ++mt)
#pragma unroll
            for (int nt = 0; nt < 2; ++nt)
                acc[mt][nt] = __builtin_amdgcn_mfma_f32_16x16x32_bf16(a[mt], b1[ks][nt], acc[mt][nt], 0, 0, 0);
    }

    // ---- prefetch phase-2 half-0 W2 fragments (latency hides under tanh + barriers) ----
    const char* w2e = (const char*)(w2t + (size_t)e * EH * DIM);
    bf16x8 b2a[4][2];
#pragma unroll
    for (int ks = 0; ks < 4; ++ks)
#pragma unroll
        for (int nt = 0; nt < 2; ++nt)
            b2a[ks][nt] = *(const bf16x8*)(w2e + (w * 64 + nt * 16 + l15) * 256 + ks * 64 + kq * 16);

    __syncthreads();   // phase-1 LDS reads complete

    // ---- h = tanh(C1 + b1) -> hT[64 tok][128 h] SWZ8 (overwrites Xs) ----
#pragma unroll
    for (int nt = 0; nt < 2; ++nt) {
        const int h = w * 32 + nt * 16 + l15;
        const float b1v = eb1[e * EH + h];
#pragma unroll
        for (int mt = 0; mt < 4; ++mt)
#pragma unroll
            for (int r = 0; r < 4; ++r) {
                int tok = mt * 16 + q4 + r;
                *(unsigned short*)(lds + SWZ8(tok * 256 + h * 2)) = f2bf(tanhf(acc[mt][nt][r] + b1v));
            }
    }
    __syncthreads();

    // ---- prefetch phase-2 half-1 W2 fragments (hides under half-0 MFMA) ----
    bf16x8 b2b[4][2];
#pragma unroll
    for (int ks = 0; ks < 4; ++ks)
#pragma unroll
        for (int nt = 0; nt < 2; ++nt)
            b2b[ks][nt] = *(const bf16x8*)(w2e + (w * 64 + 32 + nt * 16 + l15) * 256 + ks * 64 + kq * 16);

    // ---- phase 2: C2[64 tok][64 d per wave] = H @ W2, two 32-d halves ----
#pragma unroll
    for (int half = 0; half < 2; ++half) {
        auto& bsel = half ? b2b : b2a;
        f32x4 acc2[4][2];
#pragma unroll
        for (int i = 0; i < 4; ++i)
#pragma unroll
            for (int j = 0; j < 2; ++j) acc2[i][j] = zero4;
#pragma unroll
        for (int ks = 0; ks < 4; ++ks) {
            bf16x8 a[4];
#pragma unroll
            for (int mt = 0; mt < 4; ++mt)
                a[mt] = *(const bf16x8*)(lds + SWZ8((mt * 16 + l15) * 256 + ks * 64 + kq * 16));
#pragma unroll
            for (int mt = 0; mt < 4; ++mt)
#pragma unroll
                for (int nt = 0; nt < 2; ++nt)
                    acc2[mt][nt] = __builtin_amdgcn_mfma_f32_16x16x32_bf16(a[mt], bsel[ks][nt], acc2[mt][nt], 0, 0, 0);
        }
        // epilogue for this 32-d half: slot0 -> y, slot1 -> part1
        float b2v[2];
#pragma unroll
        for (int nt = 0; nt < 2; ++nt)
            b2v[nt] = eb2[e * DIM + w * 64 + half * 32 + nt * 16 + l15];
#pragma unroll
        for (int mt = 0; mt < 4; ++mt)
#pragma unroll
            for (int r = 0; r < 4; ++r) {
                int rl = mt * 16 + q4 + r;
                if (rl < cnt) {
                    int entry = wsi[WS_LIST + start + rl];
                    int tok = entry >> 1;
                    float g = wsf[WS_LIST_G + start + rl];
                    float* dst = ((entry & 1) ? part1 : y) + (size_t)tok * DIM + w * 64 + half * 32;
#pragma unroll
                    for (int nt = 0; nt < 2; ++nt)
                        dst[nt * 16 + l15] = g * (acc2[mt][nt][r] + b2v[nt]);
                }
            }
    }
}

// ---------------- Combine: y += part1 ----------------
__global__ __launch_bounds__(256) void combine_kernel(float* __restrict__ y,
                                                      const float* __restrict__ part1)
{
    const size_t i = ((size_t)blockIdx.x * 256 + threadIdx.x) * 4;
    float4 a = *(float4*)(y + i);
    const float4 b = *(const float4*)(part1 + i);
    a.x += b.x; a.y += b.y; a.z += b.z; a.w += b.w;
    *(float4*)(y + i) = a;
}

extern "C" void kernel_launch(void* const* d_in, const int* in_sizes, int n_in,
                              void* d_out, int out_size, void* d_ws, size_t ws_size,
                              hipStream_t stream)
{
    const float* x = (const float*)d_in[0];
    const float* rw1 = (const float*)d_in[1];
    const float* rb1 = (const float*)d_in[2];
    const float* rw2 = (const float*)d_in[3];
    const float* rb2 = (const float*)d_in[4];
    const float* ew1 = (const float*)d_in[5];
    const float* eb1 = (const float*)d_in[6];
    const float* ew2 = (const float*)d_in[7];
    const float* eb2 = (const float*)d_in[8];

    float* y = (float*)d_out;                       // [NT][DIM]
    float* w_out = y + (size_t)NT * DIM;            // [NT][NE]
    int* wsi = (int*)d_ws;
    float* wsf = (float*)d_ws;
    float* part1 = (float*)d_ws;                    // [NT][DIM]
    unsigned short* wsu = (unsigned short*)d_ws;

    hipMemsetAsync(wsi + WS_COUNTS, 0, NE * sizeof(int), stream);

    wprep_kernel<<<256, 256, 0, stream>>>(ew1, ew2, wsu + U_W1T, wsu + U_W2T);
    router_kernel<<<NT / 64, 256, 0, stream>>>(x, rw1, rb1, rw2, rb2, w_out, wsi, wsf);
    scan_kernel<<<1, 64, 0, stream>>>(wsi);
    scatter_kernel<<<NT / 256, 256, 0, stream>>>(wsi, wsf);
    expert_kernel<<<2 * NT / TB + NE, 256, 0, stream>>>(x, eb1, eb2, wsu + U_W1T, wsu + U_W2T,
                                                        wsi, wsf, y, part1);
    combine_kernel<<<NT * DIM / 1024, 256, 0, stream>>>(y, part1);
}

// Round 8
// 128.869 us; speedup vs baseline: 1.0694x; 1.0694x over previous
//
#include <hip/hip_runtime.h>
#include <math.h>

#define NT 32768
#define DIM 256
#define NE 16
#define EH 128
#define RH 64
#define TB 64

// ws layout: float part1[NT*DIM] first, then int/float bookkeeping, then bf16 weights
#define IB (NT * DIM)
#define WS_COUNTS (IB)
#define WS_OFFSETS (IB + 16)
#define WS_CURSORS (IB + 33)
#define WS_NBLK (IB + 49)
#define WS_TABLE (IB + 64)
#define WS_TOKE (IB + 4096)
#define WS_LIST (WS_TOKE + 2 * NT)
#define WS_TOKG (WS_LIST + 2 * NT)
#define WS_LIST_G (WS_TOKG + 2 * NT)
#define WS_END_I (WS_LIST_G + 2 * NT)
// ushort-unit offsets for bf16 transposed weights
#define U_W1T (2 * WS_END_I)
#define U_W2T (U_W1T + NE * DIM * EH)

typedef __attribute__((ext_vector_type(4))) float f32x4;
typedef __attribute__((ext_vector_type(8))) short bf16x8;
typedef __attribute__((ext_vector_type(8))) unsigned short us8;

// XOR swizzles: SWZ9 for 512B-stride tiles (row bits 9-11 -> byte bits 4-6),
//               SWZ8 for 256B-stride tiles (row bits 8-10 -> byte bits 4-6)
#define SWZ9(b) ((b) ^ (((b) >> 5) & 0x70))
#define SWZ8(b) ((b) ^ (((b) >> 4) & 0x70))

__device__ inline unsigned short f2bf(float f) {
    unsigned int bits = __builtin_bit_cast(unsigned int, f);
    bits += 0x7fffu + ((bits >> 16) & 1u);   // RNE
    return (unsigned short)(bits >> 16);
}

// ---------------- Router: w = softmax(relu(x@rw1+b1)@rw2+b2), top-2 ----------------
__global__ __launch_bounds__(256) void router_kernel(
    const float* __restrict__ x,
    const float* __restrict__ rw1, const float* __restrict__ rb1,
    const float* __restrict__ rw2, const float* __restrict__ rb2,
    float* __restrict__ w_out, int* __restrict__ wsi, float* __restrict__ wsf)
{
    __shared__ float xT[64][68];   // [d-chunk][tok]
    __shared__ float w1s[64][64];  // [d][h]
    __shared__ float hs[64][68];   // [tok][h]
    __shared__ float ls[64][20];   // [tok][e]
    __shared__ int scnt[16];

    const int tid = threadIdx.x;
    const int tok0 = blockIdx.x * 64;
    if (tid < 16) scnt[tid] = 0;

    float acc[4][4];
#pragma unroll
    for (int i = 0; i < 4; ++i)
#pragma unroll
        for (int j = 0; j < 4; ++j) acc[i][j] = 0.f;

    const int tt = (tid & 15) * 4;
    const int hh = (tid >> 4) * 4;

    for (int kc = 0; kc < 4; ++kc) {
        __syncthreads();
#pragma unroll
        for (int i = 0; i < 4; ++i) {
            int idx = tid + 256 * i;
            int t = idx >> 4;
            int d4 = (idx & 15) * 4;
            float4 v = *(const float4*)(x + (size_t)(tok0 + t) * DIM + kc * 64 + d4);
            xT[d4 + 0][t] = v.x; xT[d4 + 1][t] = v.y;
            xT[d4 + 2][t] = v.z; xT[d4 + 3][t] = v.w;
        }
#pragma unroll
        for (int i = 0; i < 4; ++i) {
            int idx = tid + 256 * i;
            int d = idx >> 4;
            int h4 = (idx & 15) * 4;
            *(float4*)&w1s[d][h4] = *(const float4*)(rw1 + (size_t)(kc * 64 + d) * RH + h4);
        }
        __syncthreads();
#pragma unroll 8
        for (int d = 0; d < 64; ++d) {
            const float4 xa4 = *(const float4*)&xT[d][tt];
            const float4 wv4 = *(const float4*)&w1s[d][hh];
            const float xa[4] = {xa4.x, xa4.y, xa4.z, xa4.w};
            const float wv[4] = {wv4.x, wv4.y, wv4.z, wv4.w};
#pragma unroll
            for (int i = 0; i < 4; ++i)
#pragma unroll
                for (int j = 0; j < 4; ++j)
                    acc[i][j] = fmaf(xa[i], wv[j], acc[i][j]);
        }
    }
    __syncthreads();
    {
        const float4 b4 = *(const float4*)(rb1 + hh);
        const float b[4] = {b4.x, b4.y, b4.z, b4.w};
#pragma unroll
        for (int i = 0; i < 4; ++i) {
            float4 hv;
            hv.x = fmaxf(acc[i][0] + b[0], 0.f);
            hv.y = fmaxf(acc[i][1] + b[1], 0.f);
            hv.z = fmaxf(acc[i][2] + b[2], 0.f);
            hv.w = fmaxf(acc[i][3] + b[3], 0.f);
            *(float4*)&hs[tt + i][hh] = hv;
        }
    }
    __syncthreads();
    {
        int tok = tid >> 2;
        int e0 = (tid & 3) * 4;
        float l[4] = {0.f, 0.f, 0.f, 0.f};
#pragma unroll 8
        for (int k = 0; k < 64; ++k) {
            float hv = hs[tok][k];
            float4 wv = *(const float4*)(rw2 + k * NE + e0);
            l[0] = fmaf(hv, wv.x, l[0]);
            l[1] = fmaf(hv, wv.y, l[1]);
            l[2] = fmaf(hv, wv.z, l[2]);
            l[3] = fmaf(hv, wv.w, l[3]);
        }
        float4 lb = *(const float4*)(rb2 + e0);
        ls[tok][e0 + 0] = l[0] + lb.x;
        ls[tok][e0 + 1] = l[1] + lb.y;
        ls[tok][e0 + 2] = l[2] + lb.z;
        ls[tok][e0 + 3] = l[3] + lb.w;
    }
    __syncthreads();
    if (tid < 64) {
        const int tok = tid;
        const int gt = tok0 + tok;
        float v[16];
        float m = -1e30f;
#pragma unroll
        for (int e = 0; e < 16; ++e) { v[e] = ls[tok][e]; m = fmaxf(m, v[e]); }
        float s = 0.f;
#pragma unroll
        for (int e = 0; e < 16; ++e) { v[e] = expf(v[e] - m); s += v[e]; }
        const float inv = 1.0f / s;
#pragma unroll
        for (int e = 0; e < 16; ++e) v[e] *= inv;
#pragma unroll
        for (int e = 0; e < 16; e += 4) {
            float4 wv = make_float4(v[e], v[e + 1], v[e + 2], v[e + 3]);
            *(float4*)(w_out + (size_t)gt * NE + e) = wv;
        }
        float v1 = -1.f, v2 = -1.f; int i1 = 0, i2 = 0;
#pragma unroll
        for (int e = 0; e < 16; ++e) {
            if (v[e] > v1) { v2 = v1; i2 = i1; v1 = v[e]; i1 = e; }
            else if (v[e] > v2) { v2 = v[e]; i2 = e; }
        }
        const float den = v1 + v2 + 1e-8f;
        atomicAdd(&scnt[i1], 1);
        atomicAdd(&scnt[i2], 1);
        wsi[WS_TOKE + 2 * gt + 0] = i1;
        wsi[WS_TOKE + 2 * gt + 1] = i2;
        wsf[WS_TOKG + 2 * gt + 0] = v1 / den;
        wsf[WS_TOKG + 2 * gt + 1] = v2 / den;
    }
    __syncthreads();
    if (tid < 16 && scnt[tid]) atomicAdd(&wsi[WS_COUNTS + tid], scnt[tid]);
}

// ---------------- Weight prep: transpose + convert to bf16 ----------------
// w1t[e][h=128][d=256] = bf16(ew1[e][d][h]);  w2t[e][d=256][k=128] = bf16(ew2[e][k][d])
__global__ __launch_bounds__(256) void wprep_kernel(
    const float* __restrict__ ew1, const float* __restrict__ ew2,
    unsigned short* __restrict__ w1t, unsigned short* __restrict__ w2t)
{
    __shared__ float t[64][65];
    int b = blockIdx.x;
    const float* src; unsigned short* dst; int R, C, tr, tc;
    if (b < 128) {                 // w1: [256 d][128 h] -> [128 h][256 d], 4x2 tiles
        int e = b >> 3, t8 = b & 7; tr = t8 >> 1; tc = t8 & 1;
        src = ew1 + (size_t)e * DIM * EH; R = DIM; C = EH;
        dst = w1t + (size_t)e * DIM * EH;
    } else {                       // w2: [128 k][256 d] -> [256 d][128 k], 2x4 tiles
        int b2 = b - 128; int e = b2 >> 3, t8 = b2 & 7; tr = t8 & 1; tc = t8 >> 1;
        src = ew2 + (size_t)e * EH * DIM; R = EH; C = DIM;
        dst = w2t + (size_t)e * EH * DIM;
    }
    const int R0 = tr * 64, C0 = tc * 64;
    const int tid = threadIdx.x;
#pragma unroll
    for (int q = 0; q < 4; ++q) {
        int r = (tid >> 4) + q * 16, c = (tid & 15) * 4;
        float4 v = *(const float4*)(src + (size_t)(R0 + r) * C + C0 + c);
        t[r][c] = v.x; t[r][c + 1] = v.y; t[r][c + 2] = v.z; t[r][c + 3] = v.w;
    }
    __syncthreads();
#pragma unroll
    for (int q = 0; q < 2; ++q) {
        int rp = (tid >> 3) + q * 32, c0 = (tid & 7) * 8;
        us8 u;
#pragma unroll
        for (int k = 0; k < 8; ++k) u[k] = f2bf(t[c0 + k][rp]);
        *(us8*)(dst + (size_t)(C0 + rp) * R + R0 + c0) = u;
    }
}

// ---------------- Scan ----------------
__global__ __launch_bounds__(64) void scan_kernel(int* __restrict__ wsi)
{
    __shared__ int soff[17], snc[16];
    const int tid = threadIdx.x;
    if (tid == 0) {
        int off = 0, nb = 0;
        soff[0] = 0;
        for (int e = 0; e < NE; ++e) {
            int c = wsi[WS_COUNTS + e];
            wsi[WS_CURSORS + e] = off;
            wsi[WS_OFFSETS + e] = off;
            off += c;
            soff[e + 1] = off;
            snc[e] = nb;
            nb += (c + TB - 1) / TB;
        }
        wsi[WS_OFFSETS + NE] = off;
        wsi[WS_NBLK] = nb;
    }
    __syncthreads();
    for (int e = 0; e < NE; ++e) {
        int nc = (soff[e + 1] - soff[e] + TB - 1) / TB;
        for (int k = tid; k < nc; k += 64)
            wsi[WS_TABLE + snc[e] + k] = (e << 16) | k;
    }
}

// ---------------- Scatter ----------------
__global__ __launch_bounds__(256) void scatter_kernel(int* __restrict__ wsi, float* __restrict__ wsf)
{
    __shared__ int scnt[16], sbase[16];
    const int tid = threadIdx.x;
    const int t = blockIdx.x * 256 + tid;
    if (tid < 16) scnt[tid] = 0;
    __syncthreads();
    const int e0 = wsi[WS_TOKE + 2 * t + 0];
    const int e1 = wsi[WS_TOKE + 2 * t + 1];
    const int l0 = atomicAdd(&scnt[e0], 1);
    const int l1 = atomicAdd(&scnt[e1], 1);
    __syncthreads();
    if (tid < 16) sbase[tid] = scnt[tid] ? atomicAdd(&wsi[WS_CURSORS + tid], scnt[tid]) : 0;
    __syncthreads();
    const int p0 = sbase[e0] + l0;
    const int p1 = sbase[e1] + l1;
    wsi[WS_LIST + p0] = (t << 1);
    wsf[WS_LIST_G + p0] = wsf[WS_TOKG + 2 * t + 0];
    wsi[WS_LIST + p1] = (t << 1) | 1;
    wsf[WS_LIST_G + p1] = wsf[WS_TOKG + 2 * t + 1];
}

// ---------------- Expert: TB=64, 4 waves, register weight-panel prefetch, no VGPR cap ----------------
__global__ __launch_bounds__(256, 1) void expert_kernel(
    const float* __restrict__ x,
    const float* __restrict__ eb1, const float* __restrict__ eb2,
    const unsigned short* __restrict__ w1t, const unsigned short* __restrict__ w2t,
    const int* __restrict__ wsi, const float* __restrict__ wsf,
    float* __restrict__ y, float* __restrict__ part1)
{
    __shared__ unsigned short smem[16384];   // 32 KB: Xs[64][256] bf16, later hT[64][128] bf16
    if ((int)blockIdx.x >= wsi[WS_NBLK]) return;

    const int ent = wsi[WS_TABLE + blockIdx.x];
    const int e = ent >> 16;
    const int c = ent & 0xffff;
    const int start = wsi[WS_OFFSETS + e] + c * TB;
    const int cnt = min(TB, wsi[WS_OFFSETS + e + 1] - start);

    const int tid = threadIdx.x;
    const int lane = tid & 63, w = tid >> 6;   // wave 0..3
    const int l15 = lane & 15;
    const int kq = lane >> 4;                   // 0..3
    const int q4 = kq * 4;
    char* lds = (char*)smem;

    // ---- issue x gather loads FIRST (16 independent float4 loads/thread) ----
    const int row = tid >> 2, q = tid & 3;
    const int srow = (row < cnt) ? (wsi[WS_LIST + start + row] >> 1) : -1;
    const float* xr = x + (size_t)(srow < 0 ? 0 : srow) * DIM + q * 64;
    float4 xa[8], xb[8];
#pragma unroll
    for (int i = 0; i < 8; ++i) {
        xa[i] = *(const float4*)(xr + i * 8);
        xb[i] = *(const float4*)(xr + i * 8 + 4);
    }

    // ---- then prefetch ALL phase-1 W1 fragments (one L2 round-trip for 8 K-steps) ----
    const char* w1e = (const char*)(w1t + (size_t)e * DIM * EH);
    bf16x8 b1[8][2];
#pragma unroll
    for (int ks = 0; ks < 8; ++ks)
#pragma unroll
        for (int nt = 0; nt < 2; ++nt)
            b1[ks][nt] = *(const bf16x8*)(w1e + (w * 32 + nt * 16 + l15) * 512 + ks * 64 + kq * 16);

    // ---- convert + stage Xs[64 tok][256 d] bf16, SWZ9 swizzled ----
    {
        const int base = row * 512 + q * 128;
#pragma unroll
        for (int i = 0; i < 8; ++i) {
            us8 u;
            if (srow >= 0) {
                u[0] = f2bf(xa[i].x); u[1] = f2bf(xa[i].y); u[2] = f2bf(xa[i].z); u[3] = f2bf(xa[i].w);
                u[4] = f2bf(xb[i].x); u[5] = f2bf(xb[i].y); u[6] = f2bf(xb[i].z); u[7] = f2bf(xb[i].w);
            } else {
#pragma unroll
                for (int k = 0; k < 8; ++k) u[k] = 0;
            }
            *(us8*)(lds + SWZ9(base + i * 16)) = u;
        }
    }
    __syncthreads();

    // ---- phase 1: C1[64 tok][32 h per wave] = X @ W1, K=256, B in registers ----
    f32x4 zero4; zero4[0] = zero4[1] = zero4[2] = zero4[3] = 0.f;
    f32x4 acc[4][2];
#pragma unroll
    for (int i = 0; i < 4; ++i)
#pragma unroll
        for (int j = 0; j < 2; ++j) acc[i][j] = zero4;

#pragma unroll
    for (int ks = 0; ks < 8; ++ks) {
        bf16x8 a[4];
#pragma unroll
        for (int mt = 0; mt < 4; ++mt)
            a[mt] = *(const bf16x8*)(lds + SWZ9((mt * 16 + l15) * 512 + ks * 64 + kq * 16));
#pragma unroll
        for (int mt = 0; mt < 4; ++mt)
#pragma unroll
            for (int nt = 0; nt < 2; ++nt)
                acc[mt][nt] = __builtin_amdgcn_mfma_f32_16x16x32_bf16(a[mt], b1[ks][nt], acc[mt][nt], 0, 0, 0);
    }

    // ---- prefetch phase-2 half-0 W2 fragments (latency hides under tanh + barrier) ----
    const char* w2e = (const char*)(w2t + (size_t)e * EH * DIM);
    bf16x8 b2a[4][2];
#pragma unroll
    for (int ks = 0; ks < 4; ++ks)
#pragma unroll
        for (int nt = 0; nt < 2; ++nt)
            b2a[ks][nt] = *(const bf16x8*)(w2e + (w * 64 + nt * 16 + l15) * 256 + ks * 64 + kq * 16);

    __syncthreads();   // phase-1 LDS reads complete

    // ---- h = tanh(C1 + b1) -> hT[64 tok][128 h] SWZ8 (overwrites Xs) ----
#pragma unroll
    for (int nt = 0; nt < 2; ++nt) {
        const int h = w * 32 + nt * 16 + l15;
        const float b1v = eb1[e * EH + h];
#pragma unroll
        for (int mt = 0; mt < 4; ++mt)
#pragma unroll
            for (int r = 0; r < 4; ++r) {
                int tok = mt * 16 + q4 + r;
                *(unsigned short*)(lds + SWZ8(tok * 256 + h * 2)) = f2bf(tanhf(acc[mt][nt][r] + b1v));
            }
    }
    __syncthreads();

    // ---- prefetch phase-2 half-1 W2 fragments (hides under half-0 MFMA) ----
    bf16x8 b2b[4][2];
#pragma unroll
    for (int ks = 0; ks < 4; ++ks)
#pragma unroll
        for (int nt = 0; nt < 2; ++nt)
            b2b[ks][nt] = *(const bf16x8*)(w2e + (w * 64 + 32 + nt * 16 + l15) * 256 + ks * 64 + kq * 16);

    // ---- phase 2 half 0 (b2a), explicit (no runtime-indexed arrays) ----
    {
        f32x4 acc2[4][2];
#pragma unroll
        for (int i = 0; i < 4; ++i)
#pragma unroll
            for (int j = 0; j < 2; ++j) acc2[i][j] = zero4;
#pragma unroll
        for (int ks = 0; ks < 4; ++ks) {
            bf16x8 a[4];
#pragma unroll
            for (int mt = 0; mt < 4; ++mt)
                a[mt] = *(const bf16x8*)(lds + SWZ8((mt * 16 + l15) * 256 + ks * 64 + kq * 16));
#pragma unroll
            for (int mt = 0; mt < 4; ++mt)
#pragma unroll
                for (int nt = 0; nt < 2; ++nt)
                    acc2[mt][nt] = __builtin_amdgcn_mfma_f32_16x16x32_bf16(a[mt], b2a[ks][nt], acc2[mt][nt], 0, 0, 0);
        }
        float b2v[2];
#pragma unroll
        for (int nt = 0; nt < 2; ++nt)
            b2v[nt] = eb2[e * DIM + w * 64 + nt * 16 + l15];
#pragma unroll
        for (int mt = 0; mt < 4; ++mt)
#pragma unroll
            for (int r = 0; r < 4; ++r) {
                int rl = mt * 16 + q4 + r;
                if (rl < cnt) {
                    int entry = wsi[WS_LIST + start + rl];
                    int tok = entry >> 1;
                    float g = wsf[WS_LIST_G + start + rl];
                    float* dst = ((entry & 1) ? part1 : y) + (size_t)tok * DIM + w * 64;
#pragma unroll
                    for (int nt = 0; nt < 2; ++nt)
                        dst[nt * 16 + l15] = g * (acc2[mt][nt][r] + b2v[nt]);
                }
            }
    }
    // ---- phase 2 half 1 (b2b) ----
    {
        f32x4 acc2[4][2];
#pragma unroll
        for (int i = 0; i < 4; ++i)
#pragma unroll
            for (int j = 0; j < 2; ++j) acc2[i][j] = zero4;
#pragma unroll
        for (int ks = 0; ks < 4; ++ks) {
            bf16x8 a[4];
#pragma unroll
            for (int mt = 0; mt < 4; ++mt)
                a[mt] = *(const bf16x8*)(lds + SWZ8((mt * 16 + l15) * 256 + ks * 64 + kq * 16));
#pragma unroll
            for (int mt = 0; mt < 4; ++mt)
#pragma unroll
                for (int nt = 0; nt < 2; ++nt)
                    acc2[mt][nt] = __builtin_amdgcn_mfma_f32_16x16x32_bf16(a[mt], b2b[ks][nt], acc2[mt][nt], 0, 0, 0);
        }
        float b2v[2];
#pragma unroll
        for (int nt = 0; nt < 2; ++nt)
            b2v[nt] = eb2[e * DIM + w * 64 + 32 + nt * 16 + l15];
#pragma unroll
        for (int mt = 0; mt < 4; ++mt)
#pragma unroll
            for (int r = 0; r < 4; ++r) {
                int rl = mt * 16 + q4 + r;
                if (rl < cnt) {
                    int entry = wsi[WS_LIST + start + rl];
                    int tok = entry >> 1;
                    float g = wsf[WS_LIST_G + start + rl];
                    float* dst = ((entry & 1) ? part1 : y) + (size_t)tok * DIM + w * 64 + 32;
#pragma unroll
                    for (int nt = 0; nt < 2; ++nt)
                        dst[nt * 16 + l15] = g * (acc2[mt][nt][r] + b2v[nt]);
                }
            }
    }
}

// ---------------- Combine: y += part1 ----------------
__global__ __launch_bounds__(256) void combine_kernel(float* __restrict__ y,
                                                      const float* __restrict__ part1)
{
    const size_t i = ((size_t)blockIdx.x * 256 + threadIdx.x) * 4;
    float4 a = *(float4*)(y + i);
    const float4 b = *(const float4*)(part1 + i);
    a.x += b.x; a.y += b.y; a.z += b.z; a.w += b.w;
    *(float4*)(y + i) = a;
}

extern "C" void kernel_launch(void* const* d_in, const int* in_sizes, int n_in,
                              void* d_out, int out_size, void* d_ws, size_t ws_size,
                              hipStream_t stream)
{
    const float* x = (const float*)d_in[0];
    const float* rw1 = (const float*)d_in[1];
    const float* rb1 = (const float*)d_in[2];
    const float* rw2 = (const float*)d_in[3];
    const float* rb2 = (const float*)d_in[4];
    const float* ew1 = (const float*)d_in[5];
    const float* eb1 = (const float*)d_in[6];
    const float* ew2 = (const float*)d_in[7];
    const float* eb2 = (const float*)d_in[8];

    float* y = (float*)d_out;                       // [NT][DIM]
    float* w_out = y + (size_t)NT * DIM;            // [NT][NE]
    int* wsi = (int*)d_ws;
    float* wsf = (float*)d_ws;
    float* part1 = (float*)d_ws;                    // [NT][DIM]
    unsigned short* wsu = (unsigned short*)d_ws;

    hipMemsetAsync(wsi + WS_COUNTS, 0, NE * sizeof(int), stream);

    wprep_kernel<<<256, 256, 0, stream>>>(ew1, ew2, wsu + U_W1T, wsu + U_W2T);
    router_kernel<<<NT / 64, 256, 0, stream>>>(x, rw1, rb1, rw2, rb2, w_out, wsi, wsf);
    scan_kernel<<<1, 64, 0, stream>>>(wsi);
    scatter_kernel<<<NT / 256, 256, 0, stream>>>(wsi, wsf);
    expert_kernel<<<2 * NT / TB + NE, 256, 0, stream>>>(x, eb1, eb2, wsu + U_W1T, wsu + U_W2T,
                                                        wsi, wsf, y, part1);
    combine_kernel<<<NT * DIM / 1024, 256, 0, stream>>>(y, part1);
}